// Round 9
// baseline (686.385 us; speedup 1.0000x reference)
//
#include <hip/hip_runtime.h>

// ParallelExpert: grouped SwiGLU MLP, E=8 experts.
//   h = x @ w1 ; h_act = silu(gate)*val ; out = h_act @ w2
// Round 8: gemm1 8-phase (T2+T3+T4+T5) KEPT; XCD swizzle REVERTED
//   (default dispatch order: concurrent window = one expert = 20 MB
//   L3-resident working set; the expert-per-XCD swizzle tripled FETCH).
// ws layout: [0,128M) hact f16; [128M,256M) w1t/w2t; [256M,288M) xh.

#define E_    8
#define T_    2048
#define DIN   1024
#define DHID  4096
#define DOUT  1024
#define INTER 8192

typedef _Float16 f16;
typedef _Float16 f16x8 __attribute__((ext_vector_type(8)));
typedef float    f32x4 __attribute__((ext_vector_type(4)));

typedef const __attribute__((address_space(1))) void gvoid_t;
typedef __attribute__((address_space(3))) void lvoid_t;

__device__ __forceinline__ void gload_lds16(const void* g, void* l) {
  __builtin_amdgcn_global_load_lds((gvoid_t*)g, (lvoid_t*)l, 16, 0, 0);
}

// ---- x f32 -> f16 bulk convert -------------------------------------------
__global__ __launch_bounds__(256) void conv_f32_f16(
    const float* __restrict__ src, f16* __restrict__ dst, int n8) {
  int i = blockIdx.x * 256 + threadIdx.x;
  int stride = gridDim.x * 256;
  for (; i < n8; i += stride) {
    const float4* s = (const float4*)(src + (size_t)i * 8);
    float4 a0 = s[0], a1 = s[1];
    f16x8 v;
    v[0] = (f16)a0.x; v[1] = (f16)a0.y; v[2] = (f16)a0.z; v[3] = (f16)a0.w;
    v[4] = (f16)a1.x; v[5] = (f16)a1.y; v[6] = (f16)a1.z; v[7] = (f16)a1.w;
    *(f16x8*)(dst + (size_t)i * 8) = v;
  }
}

// ---- transpose + convert: src f32 [E][R][C] -> dst f16 [E][C][R] ----------
__global__ __launch_bounds__(256) void xpose_f32_f16(
    const float* __restrict__ src, f16* __restrict__ dst,
    int R, int C, int tR, int tC) {
  __shared__ f16 tile[32][33];
  int bid = blockIdx.x;
  int perE = tR * tC;
  int e = bid / perE;
  int rem = bid - e * perE;
  int rt = rem / tC;
  int ct = rem - rt * tC;
  int r0 = rt * 32, c0 = ct * 32;
  int t = threadIdx.x;
  int lr = t >> 5, lc = t & 31;
  const float* s = src + (size_t)e * R * C;
  f16* d = dst + (size_t)e * C * R;
#pragma unroll
  for (int i = 0; i < 4; ++i) {
    int r = lr + 8 * i;
    tile[r][lc] = (f16)s[(size_t)(r0 + r) * C + (c0 + lc)];
  }
  __syncthreads();
#pragma unroll
  for (int i = 0; i < 4; ++i) {
    int r = lr + 8 * i;
    d[(size_t)(c0 + r) * R + (r0 + lc)] = tile[lc][r];
  }
}

// ---- GEMM1 + SwiGLU, 8-phase 256x(128+128) ---------------------------------
// xh:[E][T][DIN] f16, w1t:[E][INTER][DIN] f16, hact:[E][T][DHID] f16
__global__ __launch_bounds__(512, 2) void gemm1_swiglu_8ph(
    const f16* __restrict__ xh,
    const f16* __restrict__ w1t,
    f16* __restrict__ hact) {
  // 2-deep double buffer; rows are 64 f16 = 128 B (8 x 16B quads).
  __shared__ __align__(1024) f16 As [2][256][64];  // 64 KiB
  __shared__ __align__(1024) f16 Bgs[2][128][64];  // 32 KiB
  __shared__ __align__(1024) f16 Bvs[2][128][64];  // 32 KiB

  int bid = blockIdx.x;        // default order: concurrent window = 1 expert
  int e   = bid >> 8;
  int rem = bid & 255;
  int mt  = rem >> 5;          // 0..7  (M tiles of 256)
  int nt  = rem & 31;          // 0..31 (N tiles of 128 gate + 128 val)
  int m0 = mt * 256, n0 = nt * 128;

  const f16* xe = xh  + ((size_t)e * T_ + m0) * DIN;
  const f16* wg = w1t + ((size_t)e * INTER + n0) * DIN;
  const f16* wv = w1t + ((size_t)e * INTER + DHID + n0) * DIN;

  int tid  = threadIdx.x;
  int lane = tid & 63;
  int wid  = tid >> 6;         // 0..7
  int wm   = wid >> 2;         // 0..1 -> rows wm*128..+127
  int wn   = wid & 3;          // 0..3 -> cols wn*32..+31 (gate & val)
  int lr   = lane & 15;
  int l16  = lane >> 4;        // 0..3

  // staging geometry: each gload_lds writes one 1KB chunk (8 rows x 128B),
  // LDS dest linear, source column pre-swizzled (involution cq ^= row&7).
  int srow = lane >> 3;                  // row within chunk (0..7)
  int scol = ((lane & 7) ^ srow) * 8;    // f16 column (pre-swizzled)

  auto stageA = [&](int buf, int kt, int i) {
    int ci = wid + 8 * i;  // chunk 0..31
    gload_lds16(xe + (size_t)(ci * 8 + srow) * DIN + kt * 64 + scol,
                (char*)&As[buf][0][0] + ci * 1024);
  };
  auto stageG = [&](int buf, int kt, int i) {
    int ci = wid + 8 * i;  // chunk 0..15
    gload_lds16(wg + (size_t)(ci * 8 + srow) * DIN + kt * 64 + scol,
                (char*)&Bgs[buf][0][0] + ci * 1024);
  };
  auto stageV = [&](int buf, int kt, int i) {
    int ci = wid + 8 * i;
    gload_lds16(wv + (size_t)(ci * 8 + srow) * DIN + kt * 64 + scol,
                (char*)&Bvs[buf][0][0] + ci * 1024);
  };

  f32x4 accG[8][2], accV[8][2];
#pragma unroll
  for (int m = 0; m < 8; ++m)
#pragma unroll
    for (int n = 0; n < 2; ++n) {
      accG[m][n] = f32x4{0.f, 0.f, 0.f, 0.f};
      accV[m][n] = f32x4{0.f, 0.f, 0.f, 0.f};
    }

  f16x8 af[4][2], bg[2][2], bv[2][2];

// swizzled ds_read of an 8-f16 fragment: row, 16B-quad cq -> cq ^ (row&7)
#define READ_AF(b, MH)                                                       \
  _Pragma("unroll") for (int m = 0; m < 4; ++m)                              \
  _Pragma("unroll") for (int kk = 0; kk < 2; ++kk) {                         \
    int row_ = wm * 128 + (MH) * 64 + m * 16 + lr;                           \
    af[m][kk] = *(const f16x8*)((const char*)&As[b][0][0] + row_ * 128 +     \
                                (((kk * 4 + l16) ^ (lr & 7)) << 4));         \
  }
#define READ_B(ARR, DST, b)                                                  \
  _Pragma("unroll") for (int n = 0; n < 2; ++n)                              \
  _Pragma("unroll") for (int kk = 0; kk < 2; ++kk) {                         \
    int row_ = wn * 32 + n * 16 + lr;                                        \
    DST[n][kk] = *(const f16x8*)((const char*)&ARR[b][0][0] + row_ * 128 +   \
                                 (((kk * 4 + l16) ^ (lr & 7)) << 4));        \
  }
#define MFMA16(ACC, BB, MH)                                                  \
  __builtin_amdgcn_s_setprio(1);                                            \
  _Pragma("unroll") for (int m = 0; m < 4; ++m)                              \
  _Pragma("unroll") for (int n = 0; n < 2; ++n)                              \
  _Pragma("unroll") for (int kk = 0; kk < 2; ++kk)                          \
    ACC[(MH) * 4 + m][n] = __builtin_amdgcn_mfma_f32_16x16x32_f16(           \
        af[m][kk], BB[n][kk], ACC[(MH) * 4 + m][n], 0, 0, 0);                \
  __builtin_amdgcn_s_setprio(0);
#define BAR() __builtin_amdgcn_s_barrier()
#define LGKM0() asm volatile("s_waitcnt lgkmcnt(0)" ::: "memory")
#define VM6() asm volatile("s_waitcnt vmcnt(6)" ::: "memory")

  // ---- prologue: tile0 full (8 loads) + tile1 minus A-chunks 2,3 (6) ----
  stageA(0, 0, 0); stageA(0, 0, 1); stageA(0, 0, 2); stageA(0, 0, 3);
  stageG(0, 0, 0); stageG(0, 0, 1);
  stageV(0, 0, 0); stageV(0, 0, 1);
  stageA(1, 1, 0); stageA(1, 1, 1);
  stageG(1, 1, 0); stageG(1, 1, 1);
  stageV(1, 1, 0); stageV(1, 1, 1);
  VM6();   // drain tile0's 8 loads (keep newest 6 = tile1 partial)
  BAR();

  // ---- main loop: 16 K-tiles, 2 per iteration ----
  for (int it = 0; it < 8; ++it) {
    int tb = 2 * it + 1;          // buf1's current tile (finish A staging)
    int pa = (2 * it + 2) & 15;   // prefetch -> buf0
    int pb = (2 * it + 3) & 15;   // prefetch -> buf1

    // P1: buf0 mh0 x gate | finish A[1] <- tb (chunks 2,3)
    READ_AF(0, 0);
    READ_B(Bgs, bg, 0);
    stageA(1, tb, 2); stageA(1, tb, 3);
    BAR(); LGKM0();
    MFMA16(accG, bg, 0);
    BAR();

    // P2: buf0 mh0 x val | stage Bg[0] <- pa   (Bg[0] consumed in P1)
    READ_B(Bvs, bv, 0);
    stageG(0, pa, 0); stageG(0, pa, 1);
    BAR(); LGKM0();
    MFMA16(accV, bv, 0);
    BAR();

    // P3: buf0 mh1 x gate | stage Bv[0] <- pa  (Bv[0] consumed in P2)
    READ_AF(0, 1);
    stageV(0, pa, 0); stageV(0, pa, 1);
    BAR(); LGKM0();
    MFMA16(accG, bg, 1);
    BAR();

    // P4: buf0 mh1 x val | stage A[0] <- pa ch 0,1 (A[0] consumed in P3)
    stageA(0, pa, 0); stageA(0, pa, 1);
    BAR();
    MFMA16(accV, bv, 1);
    VM6();  // drain tile tb's loads (prev P8 + prologue/P1) -> buf1 ready
    BAR();

    // P5: buf1 mh0 x gate | stage A[0] <- pa ch 2,3
    READ_AF(1, 0);
    READ_B(Bgs, bg, 1);
    stageA(0, pa, 2); stageA(0, pa, 3);
    BAR(); LGKM0();
    MFMA16(accG, bg, 0);
    BAR();

    // P6: buf1 mh0 x val | stage Bg[1] <- pb   (Bg[1] consumed in P5)
    READ_B(Bvs, bv, 1);
    stageG(1, pb, 0); stageG(1, pb, 1);
    BAR(); LGKM0();
    MFMA16(accV, bv, 0);
    BAR();

    // P7: buf1 mh1 x gate | stage Bv[1] <- pb  (Bv[1] consumed in P6)
    READ_AF(1, 1);
    stageV(1, pb, 0); stageV(1, pb, 1);
    BAR(); LGKM0();
    MFMA16(accG, bg, 1);
    BAR();

    // P8: buf1 mh1 x val | stage A[1] <- pb ch 0,1 (A[1] consumed in P7)
    stageA(1, pb, 0); stageA(1, pb, 1);
    BAR();
    MFMA16(accV, bv, 1);
    VM6();  // drain tile pa's loads (P2..P5) -> buf0 ready for next P1
    BAR();
  }

#undef READ_AF
#undef READ_B
#undef MFMA16
#undef BAR
#undef LGKM0
#undef VM6

  // ---- epilogue: SwiGLU, store f16 ----
  // C/D 16x16 layout: col = lane&15, row = (lane>>4)*4 + reg
  f16* he = hact + (size_t)e * T_ * DHID;
  int rbase = m0 + wm * 128 + l16 * 4;
  int cbase = n0 + wn * 32 + lr;
#pragma unroll
  for (int m = 0; m < 8; ++m)
#pragma unroll
    for (int n = 0; n < 2; ++n)
#pragma unroll
      for (int j = 0; j < 4; ++j) {
        int row = rbase + m * 16 + j;
        int col = cbase + n * 16;
        float g = accG[m][n][j];
        float v = accV[m][n][j];
        float s = g / (1.0f + __expf(-g));
        he[(size_t)row * DHID + col] = (f16)(s * v);
      }
}

// ---- GEMM1 fallback (reg-staged fp32 A), used if ws too small for xh ------
__global__ __launch_bounds__(512, 2) void gemm1_swiglu_rs(
    const float* __restrict__ x,
    const f16* __restrict__ w1t,
    f16* __restrict__ hact) {
  __shared__ f16 As[128][36];
  __shared__ f16 Bg[128][32];
  __shared__ f16 Bv[128][32];

  int bid = blockIdx.x;
  int e   = bid >> 9;
  int rem = bid & 511;
  int mt  = rem >> 5;
  int nt  = rem & 31;
  int m0 = mt * 128, n0 = nt * 128;

  const float* xe = x   + ((size_t)e * T_ + m0) * DIN;
  const f16*   wg = w1t + ((size_t)e * INTER + n0) * DIN;
  const f16*   wv = w1t + ((size_t)e * INTER + DHID + n0) * DIN;

  int tid  = threadIdx.x;
  int lane = tid & 63;
  int wid  = tid >> 6;

  int arow = tid >> 2;
  int acol = (tid & 3) * 8;
  int brow = wid * 16 + (lane >> 2);
  int bcol = (lane & 3) * 8;
  f16* lG = &Bg[wid * 16][0];
  f16* lV = &Bv[wid * 16][0];

  int wm = wid >> 2;
  int wn = wid & 3;
  int lr = lane & 15;
  int lk = (lane >> 4) * 8;

  f32x4 accG[4][2], accV[4][2];
#pragma unroll
  for (int m = 0; m < 4; ++m)
#pragma unroll
    for (int n = 0; n < 2; ++n) {
      accG[m][n] = f32x4{0.f, 0.f, 0.f, 0.f};
      accV[m][n] = f32x4{0.f, 0.f, 0.f, 0.f};
    }

  for (int k = 0; k < DIN; k += 32) {
    __syncthreads();
    gload_lds16(wg + (size_t)brow * DIN + k + bcol, lG);
    gload_lds16(wv + (size_t)brow * DIN + k + bcol, lV);
    {
      const float* sa = xe + (size_t)arow * DIN + k + acol;
      float4 a0 = ((const float4*)sa)[0];
      float4 a1 = ((const float4*)sa)[1];
      f16x8 v;
      v[0] = (f16)a0.x; v[1] = (f16)a0.y; v[2] = (f16)a0.z; v[3] = (f16)a0.w;
      v[4] = (f16)a1.x; v[5] = (f16)a1.y; v[6] = (f16)a1.z; v[7] = (f16)a1.w;
      *(f16x8*)&As[arow][acol] = v;
    }
    __syncthreads();

    f16x8 af[4], bg[2], bv[2];
#pragma unroll
    for (int m = 0; m < 4; ++m)
      af[m] = *(const f16x8*)&As[wm * 64 + m * 16 + lr][lk];
#pragma unroll
    for (int n = 0; n < 2; ++n) {
      bg[n] = *(const f16x8*)&Bg[wn * 32 + n * 16 + lr][lk];
      bv[n] = *(const f16x8*)&Bv[wn * 32 + n * 16 + lr][lk];
    }
#pragma unroll
    for (int m = 0; m < 4; ++m)
#pragma unroll
      for (int n = 0; n < 2; ++n) {
        accG[m][n] = __builtin_amdgcn_mfma_f32_16x16x32_f16(af[m], bg[n], accG[m][n], 0, 0, 0);
        accV[m][n] = __builtin_amdgcn_mfma_f32_16x16x32_f16(af[m], bv[n], accV[m][n], 0, 0, 0);
      }
  }

  f16* he = hact + (size_t)e * T_ * DHID;
  int rbase = m0 + wm * 64 + (lane >> 4) * 4;
  int cbase = n0 + wn * 32 + lr;
#pragma unroll
  for (int m = 0; m < 4; ++m)
#pragma unroll
    for (int n = 0; n < 2; ++n)
#pragma unroll
      for (int j = 0; j < 4; ++j) {
        int row = rbase + m * 16 + j;
        int col = cbase + n * 16;
        float g = accG[m][n][j];
        float v = accV[m][n][j];
        float s = g / (1.0f + __expf(-g));
        he[(size_t)row * DHID + col] = (f16)(s * v);
      }
}

// ---- GEMM2: out = h_act @ w2 ----------------------------------------------
__global__ __launch_bounds__(256) void gemm2(
    const f16* __restrict__ hact,
    const f16* __restrict__ w2t,
    float* __restrict__ out) {
  __shared__ f16 As[128][32];
  __shared__ f16 Bs[128][32];

  int bid = blockIdx.x;
  int e   = bid >> 7;
  int rem = bid & 127;
  int mt  = rem >> 3;
  int nt  = rem & 7;
  int m0 = mt * 128, n0 = nt * 128;

  const f16* ha = hact + ((size_t)e * T_ + m0) * DHID;
  const f16* wb = w2t  + ((size_t)e * DOUT + n0) * DHID;

  int tid  = threadIdx.x;
  int lane = tid & 63;
  int wid  = tid >> 6;

  int srow0 = wid * 32 + (lane >> 2);
  int srow1 = srow0 + 16;
  int scol  = (lane & 3) * 8;
  f16* lA0 = &As[wid * 32][0];
  f16* lA1 = &As[wid * 32 + 16][0];
  f16* lB0 = &Bs[wid * 32][0];
  f16* lB1 = &Bs[wid * 32 + 16][0];

  int wm = wid >> 1;
  int wn = wid & 1;
  int lr = lane & 15;
  int lk = (lane >> 4) * 8;

  f32x4 acc[4][4];
#pragma unroll
  for (int m = 0; m < 4; ++m)
#pragma unroll
    for (int n = 0; n < 4; ++n) acc[m][n] = f32x4{0.f, 0.f, 0.f, 0.f};

  for (int k = 0; k < DHID; k += 32) {
    __syncthreads();
    gload_lds16(ha + (size_t)srow0 * DHID + k + scol, lA0);
    gload_lds16(ha + (size_t)srow1 * DHID + k + scol, lA1);
    gload_lds16(wb + (size_t)srow0 * DHID + k + scol, lB0);
    gload_lds16(wb + (size_t)srow1 * DHID + k + scol, lB1);
    __syncthreads();

    f16x8 af[4], bf[4];
#pragma unroll
    for (int m = 0; m < 4; ++m)
      af[m] = *(const f16x8*)&As[wm * 64 + m * 16 + lr][lk];
#pragma unroll
    for (int n = 0; n < 4; ++n)
      bf[n] = *(const f16x8*)&Bs[wn * 64 + n * 16 + lr][lk];
#pragma unroll
    for (int m = 0; m < 4; ++m)
#pragma unroll
      for (int n = 0; n < 4; ++n)
        acc[m][n] = __builtin_amdgcn_mfma_f32_16x16x32_f16(af[m], bf[n], acc[m][n], 0, 0, 0);
  }

  float* oe = out + (size_t)e * T_ * DOUT;
  int rbase = m0 + wm * 64 + (lane >> 4) * 4;
  int cbase = n0 + wn * 64 + lr;
#pragma unroll
  for (int m = 0; m < 4; ++m)
#pragma unroll
    for (int n = 0; n < 4; ++n)
#pragma unroll
      for (int j = 0; j < 4; ++j) {
        int row = rbase + m * 16 + j;
        int col = cbase + n * 16;
        oe[(size_t)row * DOUT + col] = acc[m][n][j];
      }
}

extern "C" void kernel_launch(void* const* d_in, const int* in_sizes, int n_in,
                              void* d_out, int out_size, void* d_ws, size_t ws_size,
                              hipStream_t stream) {
  const float* x  = (const float*)d_in[0];
  const float* w1 = (const float*)d_in[1];
  const float* w2 = (const float*)d_in[2];
  float* out = (float*)d_out;

  const size_t HACT_B = (size_t)E_ * T_ * DHID * 2;    // 128 MB
  const size_t WT_B   = (size_t)E_ * INTER * DIN * 2;  // 128 MB
  const size_t XH_B   = (size_t)E_ * T_ * DIN * 2;     //  32 MB

  f16* hact = (f16*)d_ws;
  f16* wt   = (f16*)((char*)d_ws + HACT_B);

  // 1) w1 [E][DIN][INTER] -> w1t [E][INTER][DIN] (f16)
  xpose_f32_f16<<<E_ * (DIN / 32) * (INTER / 32), 256, 0, stream>>>(
      w1, wt, DIN, INTER, DIN / 32, INTER / 32);

  // 2) fused GEMM1 + SwiGLU
  if (ws_size >= HACT_B + WT_B + XH_B) {
    f16* xxh = (f16*)((char*)d_ws + HACT_B + WT_B);
    conv_f32_f16<<<2048, 256, 0, stream>>>(x, xxh, E_ * T_ * DIN / 8);
    gemm1_swiglu_8ph<<<E_ * 8 * 32, 512, 0, stream>>>(xxh, wt, hact);
  } else {
    gemm1_swiglu_rs<<<E_ * 16 * 32, 512, 0, stream>>>(x, wt, hact);
  }

  // 3) w2 [E][DHID][DOUT] -> w2t [E][DOUT][DHID] (f16), reusing wt region
  xpose_f32_f16<<<E_ * (DHID / 32) * (DOUT / 32), 256, 0, stream>>>(
      w2, wt, DHID, DOUT, DHID / 32, DOUT / 32);
  // 4) GEMM2
  gemm2<<<E_ * 16 * 8, 256, 0, stream>>>(hact, wt, out);
}

// Round 11
// 600.418 us; speedup vs baseline: 1.1432x; 1.1432x over previous
//
#include <hip/hip_runtime.h>

// ParallelExpert: grouped SwiGLU MLP, E=8 experts.
//   h = x @ w1 ; h_act = silu(gate)*val ; out = h_act @ w2
// Round 11: gemm2_8ph FIXED (r10 had two bugs vs the proven gemm1_8ph
//   skeleton): (1) single bf reg set clobbered in P2 but reused in P3 ->
//   now persistent bf0/bf1 per N-quadrant, like gemm1's bg/bv; (2) P2/P6
//   staged B rows concurrently ds_read in the same phase -> staging moved
//   to phases where the region is dead (B: P3/P4, A: P4/P5; mirrored P7/P8).
//   vmcnt ledger re-derived: VM6 at P4/P8 drains exactly the consumed
//   tile's 8 loads; steady state 6 in flight matches prologue.
// gemm1 stays 2-phase 128^2 (K=1024: 8-phase regressed, r9).
// ws layout: [0,128M) hact f16; [128M,256M) w1t/w2t; [256M,288M) xh.

#define E_    8
#define T_    2048
#define DIN   1024
#define DHID  4096
#define DOUT  1024
#define INTER 8192

typedef _Float16 f16;
typedef _Float16 f16x8 __attribute__((ext_vector_type(8)));
typedef float    f32x4 __attribute__((ext_vector_type(4)));

typedef const __attribute__((address_space(1))) void gvoid_t;
typedef __attribute__((address_space(3))) void lvoid_t;

__device__ __forceinline__ void gload_lds16(const void* g, void* l) {
  __builtin_amdgcn_global_load_lds((gvoid_t*)g, (lvoid_t*)l, 16, 0, 0);
}

// ---- x f32 -> f16 bulk convert -------------------------------------------
__global__ __launch_bounds__(256) void conv_f32_f16(
    const float* __restrict__ src, f16* __restrict__ dst, int n8) {
  int i = blockIdx.x * 256 + threadIdx.x;
  int stride = gridDim.x * 256;
  for (; i < n8; i += stride) {
    const float4* s = (const float4*)(src + (size_t)i * 8);
    float4 a0 = s[0], a1 = s[1];
    f16x8 v;
    v[0] = (f16)a0.x; v[1] = (f16)a0.y; v[2] = (f16)a0.z; v[3] = (f16)a0.w;
    v[4] = (f16)a1.x; v[5] = (f16)a1.y; v[6] = (f16)a1.z; v[7] = (f16)a1.w;
    *(f16x8*)(dst + (size_t)i * 8) = v;
  }
}

// ---- transpose + convert: src f32 [E][R][C] -> dst f16 [E][C][R] ----------
__global__ __launch_bounds__(256) void xpose_f32_f16(
    const float* __restrict__ src, f16* __restrict__ dst,
    int R, int C, int tR, int tC) {
  __shared__ f16 tile[32][33];
  int bid = blockIdx.x;
  int perE = tR * tC;
  int e = bid / perE;
  int rem = bid - e * perE;
  int rt = rem / tC;
  int ct = rem - rt * tC;
  int r0 = rt * 32, c0 = ct * 32;
  int t = threadIdx.x;
  int lr = t >> 5, lc = t & 31;
  const float* s = src + (size_t)e * R * C;
  f16* d = dst + (size_t)e * C * R;
#pragma unroll
  for (int i = 0; i < 4; ++i) {
    int r = lr + 8 * i;
    tile[r][lc] = (f16)s[(size_t)(r0 + r) * C + (c0 + lc)];
  }
  __syncthreads();
#pragma unroll
  for (int i = 0; i < 4; ++i) {
    int r = lr + 8 * i;
    d[(size_t)(c0 + r) * R + (r0 + lc)] = tile[lc][r];
  }
}

// ---- GEMM1 + SwiGLU (2-phase, round-6 proven) -----------------------------
__global__ __launch_bounds__(512, 2) void gemm1_swiglu_xh(
    const f16* __restrict__ xh,
    const f16* __restrict__ w1t,
    f16* __restrict__ hact) {
  __shared__ f16 As[128][32];
  __shared__ f16 Bg[128][32];
  __shared__ f16 Bv[128][32];

  int bid = blockIdx.x;
  int e   = bid >> 9;
  int rem = bid & 511;
  int mt  = rem >> 5;
  int nt  = rem & 31;
  int m0 = mt * 128, n0 = nt * 128;

  const f16* xe = xh  + ((size_t)e * T_ + m0) * DIN;
  const f16* wg = w1t + ((size_t)e * INTER + n0) * DIN;
  const f16* wv = w1t + ((size_t)e * INTER + DHID + n0) * DIN;

  int tid  = threadIdx.x;
  int lane = tid & 63;
  int wid  = tid >> 6;           // 0..7

  int srow = wid * 16 + (lane >> 2);
  int scol = (lane & 3) * 8;
  f16* lA = &As[wid * 16][0];
  f16* lG = &Bg[wid * 16][0];
  f16* lV = &Bv[wid * 16][0];

  int wm = wid >> 2;             // 0..1
  int wn = wid & 3;              // 0..3
  int lr = lane & 15;
  int lk = (lane >> 4) * 8;

  f32x4 accG[4][2], accV[4][2];
#pragma unroll
  for (int m = 0; m < 4; ++m)
#pragma unroll
    for (int n = 0; n < 2; ++n) {
      accG[m][n] = f32x4{0.f, 0.f, 0.f, 0.f};
      accV[m][n] = f32x4{0.f, 0.f, 0.f, 0.f};
    }

  for (int k = 0; k < DIN; k += 32) {
    __syncthreads();
    gload_lds16(xe + (size_t)srow * DIN + k + scol, lA);
    gload_lds16(wg + (size_t)srow * DIN + k + scol, lG);
    gload_lds16(wv + (size_t)srow * DIN + k + scol, lV);
    __syncthreads();

    f16x8 af[4], bg[2], bv[2];
#pragma unroll
    for (int m = 0; m < 4; ++m)
      af[m] = *(const f16x8*)&As[wm * 64 + m * 16 + lr][lk];
#pragma unroll
    for (int n = 0; n < 2; ++n) {
      bg[n] = *(const f16x8*)&Bg[wn * 32 + n * 16 + lr][lk];
      bv[n] = *(const f16x8*)&Bv[wn * 32 + n * 16 + lr][lk];
    }
#pragma unroll
    for (int m = 0; m < 4; ++m)
#pragma unroll
      for (int n = 0; n < 2; ++n) {
        accG[m][n] = __builtin_amdgcn_mfma_f32_16x16x32_f16(af[m], bg[n], accG[m][n], 0, 0, 0);
        accV[m][n] = __builtin_amdgcn_mfma_f32_16x16x32_f16(af[m], bv[n], accV[m][n], 0, 0, 0);
      }
  }

  f16* he = hact + (size_t)e * T_ * DHID;
  int rbase = m0 + wm * 64 + (lane >> 4) * 4;
  int cbase = n0 + wn * 32 + lr;
#pragma unroll
  for (int m = 0; m < 4; ++m)
#pragma unroll
    for (int n = 0; n < 2; ++n)
#pragma unroll
      for (int j = 0; j < 4; ++j) {
        int row = rbase + m * 16 + j;
        int col = cbase + n * 16;
        float g = accG[m][n][j];
        float v = accV[m][n][j];
        float s = g / (1.0f + __expf(-g));
        he[(size_t)row * DHID + col] = (f16)(s * v);
      }
}

// ---- GEMM1 fallback (reg-staged fp32 A), used if ws too small for xh ------
__global__ __launch_bounds__(512, 2) void gemm1_swiglu_rs(
    const float* __restrict__ x,
    const f16* __restrict__ w1t,
    f16* __restrict__ hact) {
  __shared__ f16 As[128][36];
  __shared__ f16 Bg[128][32];
  __shared__ f16 Bv[128][32];

  int bid = blockIdx.x;
  int e   = bid >> 9;
  int rem = bid & 511;
  int mt  = rem >> 5;
  int nt  = rem & 31;
  int m0 = mt * 128, n0 = nt * 128;

  const float* xe = x   + ((size_t)e * T_ + m0) * DIN;
  const f16*   wg = w1t + ((size_t)e * INTER + n0) * DIN;
  const f16*   wv = w1t + ((size_t)e * INTER + DHID + n0) * DIN;

  int tid  = threadIdx.x;
  int lane = tid & 63;
  int wid  = tid >> 6;

  int arow = tid >> 2;
  int acol = (tid & 3) * 8;
  int brow = wid * 16 + (lane >> 2);
  int bcol = (lane & 3) * 8;
  f16* lG = &Bg[wid * 16][0];
  f16* lV = &Bv[wid * 16][0];

  int wm = wid >> 2;
  int wn = wid & 3;
  int lr = lane & 15;
  int lk = (lane >> 4) * 8;

  f32x4 accG[4][2], accV[4][2];
#pragma unroll
  for (int m = 0; m < 4; ++m)
#pragma unroll
    for (int n = 0; n < 2; ++n) {
      accG[m][n] = f32x4{0.f, 0.f, 0.f, 0.f};
      accV[m][n] = f32x4{0.f, 0.f, 0.f, 0.f};
    }

  for (int k = 0; k < DIN; k += 32) {
    __syncthreads();
    gload_lds16(wg + (size_t)brow * DIN + k + bcol, lG);
    gload_lds16(wv + (size_t)brow * DIN + k + bcol, lV);
    {
      const float* sa = xe + (size_t)arow * DIN + k + acol;
      float4 a0 = ((const float4*)sa)[0];
      float4 a1 = ((const float4*)sa)[1];
      f16x8 v;
      v[0] = (f16)a0.x; v[1] = (f16)a0.y; v[2] = (f16)a0.z; v[3] = (f16)a0.w;
      v[4] = (f16)a1.x; v[5] = (f16)a1.y; v[6] = (f16)a1.z; v[7] = (f16)a1.w;
      *(f16x8*)&As[arow][acol] = v;
    }
    __syncthreads();

    f16x8 af[4], bg[2], bv[2];
#pragma unroll
    for (int m = 0; m < 4; ++m)
      af[m] = *(const f16x8*)&As[wm * 64 + m * 16 + lr][lk];
#pragma unroll
    for (int n = 0; n < 2; ++n) {
      bg[n] = *(const f16x8*)&Bg[wn * 32 + n * 16 + lr][lk];
      bv[n] = *(const f16x8*)&Bv[wn * 32 + n * 16 + lr][lk];
    }
#pragma unroll
    for (int m = 0; m < 4; ++m)
#pragma unroll
      for (int n = 0; n < 2; ++n) {
        accG[m][n] = __builtin_amdgcn_mfma_f32_16x16x32_f16(af[m], bg[n], accG[m][n], 0, 0, 0);
        accV[m][n] = __builtin_amdgcn_mfma_f32_16x16x32_f16(af[m], bv[n], accV[m][n], 0, 0, 0);
      }
  }

  f16* he = hact + (size_t)e * T_ * DHID;
  int rbase = m0 + wm * 64 + (lane >> 4) * 4;
  int cbase = n0 + wn * 32 + lr;
#pragma unroll
  for (int m = 0; m < 4; ++m)
#pragma unroll
    for (int n = 0; n < 2; ++n)
#pragma unroll
      for (int j = 0; j < 4; ++j) {
        int row = rbase + m * 16 + j;
        int col = cbase + n * 16;
        float g = accG[m][n][j];
        float v = accV[m][n][j];
        float s = g / (1.0f + __expf(-g));
        he[(size_t)row * DHID + col] = (f16)(s * v);
      }
}

// ---- GEMM2, 8-phase 256x256 (K=4096 = 64 K-tiles) -------------------------
// hact:[E][T][DHID] f16, w2t:[E][DOUT][DHID] f16, out:[E][T][DOUT] f32
// Persistent bf0 (N-quadrant 0) / bf1 (quadrant 1) like gemm1's bg/bv.
// Staging only into dead LDS regions: B-buf dead after its P2/P6 reads,
// A-buf dead after its P3/P7 reads.
__global__ __launch_bounds__(512, 2) void gemm2_8ph(
    const f16* __restrict__ hact,
    const f16* __restrict__ w2t,
    float* __restrict__ out) {
  __shared__ __align__(1024) f16 As[2][256][64];  // 64 KiB
  __shared__ __align__(1024) f16 Bs[2][256][64];  // 64 KiB

  int bid = blockIdx.x;
  int e   = bid >> 5;
  int rem = bid & 31;
  int mt  = rem >> 2;          // 0..7 (M tiles of 256)
  int nt  = rem & 3;           // 0..3 (N tiles of 256)
  int m0 = mt * 256, n0 = nt * 256;

  const f16* ha = hact + ((size_t)e * T_ + m0) * DHID;
  const f16* wb = w2t  + ((size_t)e * DOUT + n0) * DHID;

  int tid  = threadIdx.x;
  int lane = tid & 63;
  int wid  = tid >> 6;         // 0..7
  int wm   = wid >> 2;         // 0..1 -> rows wm*128..+127
  int wn   = wid & 3;          // 0..3 -> cols wn*64..+63
  int lr   = lane & 15;
  int l16  = lane >> 4;        // 0..3

  // staging: 1KB chunk = 8 rows x 128B; linear LDS dest, pre-swizzled source
  int srow = lane >> 3;                  // 0..7
  int scol = ((lane & 7) ^ srow) * 8;    // involution cq ^= row&7

  auto stA = [&](int buf, int kt, int i) {
    int ci = wid + 8 * i;  // chunk 0..31 (rows ci*8..ci*8+7)
    gload_lds16(ha + (size_t)(ci * 8 + srow) * DHID + kt * 64 + scol,
                (char*)&As[buf][0][0] + ci * 1024);
  };
  auto stB = [&](int buf, int kt, int i) {
    int ci = wid + 8 * i;
    gload_lds16(wb + (size_t)(ci * 8 + srow) * DHID + kt * 64 + scol,
                (char*)&Bs[buf][0][0] + ci * 1024);
  };

  f32x4 acc[8][4];
#pragma unroll
  for (int m = 0; m < 8; ++m)
#pragma unroll
    for (int n = 0; n < 4; ++n) acc[m][n] = f32x4{0.f, 0.f, 0.f, 0.f};

  f16x8 af[4][2], bf0[2][2], bf1[2][2];

#define READ_A2(b, MH)                                                       \
  _Pragma("unroll") for (int m = 0; m < 4; ++m)                              \
  _Pragma("unroll") for (int kk = 0; kk < 2; ++kk) {                         \
    int row_ = wm * 128 + (MH) * 64 + m * 16 + lr;                           \
    af[m][kk] = *(const f16x8*)((const char*)&As[b][0][0] + row_ * 128 +     \
                                (((kk * 4 + l16) ^ (lr & 7)) << 4));         \
  }
#define READ_B2(b, NH, DST)                                                  \
  _Pragma("unroll") for (int n = 0; n < 2; ++n)                              \
  _Pragma("unroll") for (int kk = 0; kk < 2; ++kk) {                         \
    int row_ = wn * 64 + (NH) * 32 + n * 16 + lr;                            \
    DST[n][kk] = *(const f16x8*)((const char*)&Bs[b][0][0] + row_ * 128 +    \
                                 (((kk * 4 + l16) ^ (lr & 7)) << 4));        \
  }
#define MFMA16Q(MH, NH, BB)                                                  \
  __builtin_amdgcn_s_setprio(1);                                            \
  _Pragma("unroll") for (int m = 0; m < 4; ++m)                              \
  _Pragma("unroll") for (int n = 0; n < 2; ++n)                              \
  _Pragma("unroll") for (int kk = 0; kk < 2; ++kk)                          \
    acc[(MH) * 4 + m][(NH) * 2 + n] = __builtin_amdgcn_mfma_f32_16x16x32_f16(\
        af[m][kk], BB[n][kk], acc[(MH) * 4 + m][(NH) * 2 + n], 0, 0, 0);     \
  __builtin_amdgcn_s_setprio(0);
#define BAR() __builtin_amdgcn_s_barrier()
#define LGKM0() asm volatile("s_waitcnt lgkmcnt(0)" ::: "memory")
#define VM6() asm volatile("s_waitcnt vmcnt(6)" ::: "memory")

  // ---- prologue: tile0 full (8) + tile1 partial (B x4 + A ch0,1 = 6) ----
  stA(0, 0, 0); stA(0, 0, 1); stA(0, 0, 2); stA(0, 0, 3);
  stB(0, 0, 0); stB(0, 0, 1); stB(0, 0, 2); stB(0, 0, 3);
  stB(1, 1, 0); stB(1, 1, 1); stB(1, 1, 2); stB(1, 1, 3);
  stA(1, 1, 0); stA(1, 1, 1);
  VM6();   // drain tile0's 8 (keep tile1's 6 in flight)
  BAR();

  // ---- main loop: 64 K-tiles, 2 per iteration ----
  for (int it = 0; it < 32; ++it) {
    int tb = 2 * it + 1;
    int pa = (2 * it + 2) & 63;
    int pb = (2 * it + 3) & 63;

    // P1: buf0 Q(0,0) | finish tile tb: A ch2,3
    READ_A2(0, 0); READ_B2(0, 0, bf0);
    stA(1, tb, 2); stA(1, tb, 3);
    BAR(); LGKM0();
    MFMA16Q(0, 0, bf0);
    BAR();

    // P2: buf0 Q(0,1) | (no staging: B-buf0 rows still being read here)
    READ_B2(0, 1, bf1);
    BAR(); LGKM0();
    MFMA16Q(0, 1, bf1);
    BAR();

    // P3: buf0 Q(1,0) reuses bf0 | stage pa B01 (B-buf0 dead after P2)
    READ_A2(0, 1);
    stB(0, pa, 0); stB(0, pa, 1);
    BAR(); LGKM0();
    MFMA16Q(1, 0, bf0);
    BAR();

    // P4: buf0 Q(1,1) reuses bf1 | stage pa B23 + A01 (A-buf0 dead after P3)
    stB(0, pa, 2); stB(0, pa, 3);
    stA(0, pa, 0); stA(0, pa, 1);
    BAR();
    MFMA16Q(1, 1, bf1);
    VM6();  // drain tile tb's 8 -> buf1 ready
    BAR();

    // P5: buf1 Q(0,0) | stage pa A23
    READ_A2(1, 0); READ_B2(1, 0, bf0);
    stA(0, pa, 2); stA(0, pa, 3);
    BAR(); LGKM0();
    MFMA16Q(0, 0, bf0);
    BAR();

    // P6: buf1 Q(0,1) | (no staging)
    READ_B2(1, 1, bf1);
    BAR(); LGKM0();
    MFMA16Q(0, 1, bf1);
    BAR();

    // P7: buf1 Q(1,0) reuses bf0 | stage pb B01
    READ_A2(1, 1);
    stB(1, pb, 0); stB(1, pb, 1);
    BAR(); LGKM0();
    MFMA16Q(1, 0, bf0);
    BAR();

    // P8: buf1 Q(1,1) reuses bf1 | stage pb B23 + A01
    stB(1, pb, 2); stB(1, pb, 3);
    stA(1, pb, 0); stA(1, pb, 1);
    BAR();
    MFMA16Q(1, 1, bf1);
    VM6();  // drain tile pa's 8 -> buf0 ready
    BAR();
  }

#undef READ_A2
#undef READ_B2
#undef MFMA16Q
#undef BAR
#undef LGKM0
#undef VM6

  // ---- epilogue: fp32 store ----
  float* oe = out + (size_t)e * T_ * DOUT;
  int rbase = m0 + wm * 128 + l16 * 4;
  int cbase = n0 + wn * 64 + lr;
#pragma unroll
  for (int m = 0; m < 8; ++m)
#pragma unroll
    for (int n = 0; n < 4; ++n)
#pragma unroll
      for (int j = 0; j < 4; ++j) {
        int row = rbase + m * 16 + j;
        int col = cbase + n * 16;
        oe[(size_t)row * DOUT + col] = acc[m][n][j];
      }
}

extern "C" void kernel_launch(void* const* d_in, const int* in_sizes, int n_in,
                              void* d_out, int out_size, void* d_ws, size_t ws_size,
                              hipStream_t stream) {
  const float* x  = (const float*)d_in[0];
  const float* w1 = (const float*)d_in[1];
  const float* w2 = (const float*)d_in[2];
  float* out = (float*)d_out;

  const size_t HACT_B = (size_t)E_ * T_ * DHID * 2;    // 128 MB
  const size_t WT_B   = (size_t)E_ * INTER * DIN * 2;  // 128 MB
  const size_t XH_B   = (size_t)E_ * T_ * DIN * 2;     //  32 MB

  f16* hact = (f16*)d_ws;
  f16* wt   = (f16*)((char*)d_ws + HACT_B);

  // 1) w1 [E][DIN][INTER] -> w1t [E][INTER][DIN] (f16)
  xpose_f32_f16<<<E_ * (DIN / 32) * (INTER / 32), 256, 0, stream>>>(
      w1, wt, DIN, INTER, DIN / 32, INTER / 32);

  // 2) fused GEMM1 + SwiGLU (2-phase)
  if (ws_size >= HACT_B + WT_B + XH_B) {
    f16* xxh = (f16*)((char*)d_ws + HACT_B + WT_B);
    conv_f32_f16<<<2048, 256, 0, stream>>>(x, xxh, E_ * T_ * DIN / 8);
    gemm1_swiglu_xh<<<E_ * 16 * 32, 512, 0, stream>>>(xxh, wt, hact);
  } else {
    gemm1_swiglu_rs<<<E_ * 16 * 32, 512, 0, stream>>>(x, wt, hact);
  }

  // 3) w2 [E][DHID][DOUT] -> w2t [E][DOUT][DHID] (f16), reusing wt region
  xpose_f32_f16<<<E_ * (DHID / 32) * (DOUT / 32), 256, 0, stream>>>(
      w2, wt, DHID, DOUT, DHID / 32, DOUT / 32);
  // 4) GEMM2 (8-phase, 256^2, 256 blocks = 1/CU)
  gemm2_8ph<<<E_ * 8 * 4, 512, 0, stream>>>(hact, wt, out);
}